// Round 8
// baseline (118.780 us; speedup 1.0000x reference)
//
#include <hip/hip_runtime.h>
#include <utility>

#define FIELD 39
#define DIM   16
#define BATCH 8192
#define EPAD  42      // 39 real + 3 zero pad (padded quads may index up to 41)

// ---- flat row-padded weight layout: row i holds w(i, i+1..38), padded to x4 ----
constexpr int widx(int i, int j) { return i*(FIELD-1) - i*(i-1)/2 + (j-i-1); }
constexpr int ceil4(int x) { return (x+3) & ~3; }
constexpr int rowlen(int i) { return ceil4(FIELD - 1 - i); }        // i = 0..37
constexpr int rowstart(int i) {
    int s = 0; for (int m = 0; m < i; ++m) s += rowlen(m); return s;
}
constexpr int WTOT = rowstart(FIELD - 1);                           // 800 floats

struct WMap { int v[WTOT]; };
constexpr WMap make_map() {
    WMap m{};
    for (int i = 0; i < WTOT; ++i) m.v[i] = -1;                     // -1 -> 0.0f pad
    for (int i = 0; i < FIELD - 1; ++i)
        for (int k = 0; k < FIELD - 1 - i; ++k)
            m.v[rowstart(i) + k] = widx(i, i + 1 + k);
    return m;
}
__device__ constexpr WMap g_map = make_map();

// ---- pair-loop machinery: every index a literal after instantiation ----
__device__ __forceinline__ float4 ld4(const float* lds, int ofs) {
    return *reinterpret_cast<const float4*>(lds + ofs);   // ds_read_b128, imm offset
}
template <int EB>
__device__ __forceinline__ float fma4(float4 w, const float (&e)[EPAD], float s) {
    s = fmaf(w.x, e[EB+0], s); s = fmaf(w.y, e[EB+1], s);
    s = fmaf(w.z, e[EB+2], s); s = fmaf(w.w, e[EB+3], s);
    return s;
}
template <int I, size_t... Qs>
__device__ __forceinline__ float row_sum(const float* lds, const float (&e)[EPAD],
                                         std::index_sequence<Qs...>) {
    float s = 0.f;
    ((s = fma4<I + 1 + 4*(int)Qs>(ld4(lds, rowstart(I) + 4*(int)Qs), e, s)), ...);
    return s;
}
template <size_t... Is>
__device__ __forceinline__ float pair_sum(const float* lds, const float (&e)[EPAD],
                                          std::index_sequence<Is...>) {
    float acc[4] = {0.f, 0.f, 0.f, 0.f};
    ((acc[Is & 3] = fmaf(e[Is],
         row_sum<(int)Is>(lds, e, std::make_index_sequence<(size_t)(rowlen((int)Is)/4)>{}),
         acc[Is & 3])), ...);
    return (acc[0] + acc[1]) + (acc[2] + acc[3]);
}
template <size_t... Fs>
__device__ __forceinline__ void gather_all(const int (&idx)[FIELD],
                                           const float* __restrict__ emb,
                                           int d, float (&e)[EPAD],
                                           std::index_sequence<Fs...>) {
    // single-use random lines: non-temporal keeps L2 for lw / inputs
    ((e[Fs] = __builtin_nontemporal_load(emb + (size_t)idx[Fs] * DIM + d)), ...);
}
template <size_t... Fs>
__device__ __forceinline__ void load_idx(const int* __restrict__ rowIdx,
                                         int (&idx)[FIELD], std::index_sequence<Fs...>) {
    ((idx[Fs] = rowIdx[Fs]), ...);                        // merged dwordx4
}

// 4 rows/wave, lane = rloc*16 + d. e[] in VGPRs (flat, fold-expr indices only);
// fw packed+padded in LDS read as aligned broadcast float4 with imm offsets.
__global__ __launch_bounds__(256, 2) void fwfm_kernel(
    const int*   __restrict__ inputs,   // [BATCH][FIELD]
    const float* __restrict__ emb,      // [1M][DIM]
    const float* __restrict__ fw,       // [741]
    const float* __restrict__ lw,       // [1M]
    const float* __restrict__ bias,     // [1]
    float*       __restrict__ out)      // [BATCH]
{
    __shared__ __align__(16) float wlds[WTOT];            // 3.2 KB

    const int tid  = threadIdx.x;
    const int lane = tid & 63;
    const int wave = tid >> 6;
    const int d    = lane & 15;
    const int rloc = lane >> 4;
    const int row  = blockIdx.x * 16 + wave * 4 + rloc;

    const int* rowIdx = inputs + row * FIELD;

    // ---- issue the long-latency random gathers FIRST ----
    int idx[FIELD];
    load_idx(rowIdx, idx, std::make_index_sequence<FIELD>{});
    float e[EPAD];
    gather_all(idx, emb, d, e, std::make_index_sequence<FIELD>{});
    e[39] = 0.f; e[40] = 0.f; e[41] = 0.f;

    // ---- first-order gathers (overlap with emb gathers in flight) ----
    float l0 = lw[idx[d]], l1 = lw[idx[d + 16]];
    float l2 = (d < 7) ? lw[idx[d + 32]] : 0.f;

    // ---- stage packed weights into LDS (also overlaps gather latency) ----
    for (int s = tid; s < WTOT; s += 256) {
        int m = g_map.v[s];
        wlds[s] = (m >= 0) ? fw[m] : 0.f;
    }
    __syncthreads();

    // ---- second order: 38 padded rows of broadcast float4 ----
    float so = pair_sum(wlds, e, std::make_index_sequence<FIELD - 1>{});

    // ---- reduce the 16 dim-lanes of this row ----
    float tot = so + (l0 + l1 + l2);
    tot += __shfl_xor(tot, 1, 64);
    tot += __shfl_xor(tot, 2, 64);
    tot += __shfl_xor(tot, 4, 64);
    tot += __shfl_xor(tot, 8, 64);

    if (d == 0) out[row] = tot + bias[0];
}

extern "C" void kernel_launch(void* const* d_in, const int* in_sizes, int n_in,
                              void* d_out, int out_size, void* d_ws, size_t ws_size,
                              hipStream_t stream) {
    const int*   inputs = (const int*)  d_in[0];
    const float* emb    = (const float*)d_in[1];
    const float* fw     = (const float*)d_in[2];
    const float* lw     = (const float*)d_in[3];
    const float* bias   = (const float*)d_in[4];
    float*       out    = (float*)      d_out;

    dim3 grid(BATCH / 16);   // 512 blocks * 4 waves * 4 rows = 8192 rows
    fwfm_kernel<<<grid, 256, 0, stream>>>(inputs, emb, fw, lw, bias, out);
}

// Round 9
// 113.064 us; speedup vs baseline: 1.0506x; 1.0506x over previous
//
#include <hip/hip_runtime.h>
#include <utility>

#define FIELD 39
#define DIM   16
#define BATCH 8192
#define EPAD  42      // 39 real + 3 zero pad (padded quads may index up to 41)
#define RPW   8       // rows per wave: lane = rloc*8 + dh, dh owns dims {2dh, 2dh+1}

// ---- flat row-padded weight layout: row i holds w(i, i+1..38), padded to x4 ----
constexpr int widx(int i, int j) { return i*(FIELD-1) - i*(i-1)/2 + (j-i-1); }
constexpr int ceil4(int x) { return (x+3) & ~3; }
constexpr int rowlen(int i) { return ceil4(FIELD - 1 - i); }        // i = 0..37
constexpr int rowstart(int i) {
    int s = 0; for (int m = 0; m < i; ++m) s += rowlen(m); return s;
}
constexpr int WTOT = rowstart(FIELD - 1);                           // 800 floats

struct WMap { int v[WTOT]; };
constexpr WMap make_map() {
    WMap m{};
    for (int i = 0; i < WTOT; ++i) m.v[i] = -1;                     // -1 -> 0.0f pad
    for (int i = 0; i < FIELD - 1; ++i)
        for (int k = 0; k < FIELD - 1 - i; ++k)
            m.v[rowstart(i) + k] = widx(i, i + 1 + k);
    return m;
}
__device__ constexpr WMap g_map = make_map();

struct f2 { float x, y; };   // dim pair (2dh, 2dh+1)

// ---- pair-loop machinery: every index a literal after instantiation ----
__device__ __forceinline__ float4 ld4(const float* lds, int ofs) {
    return *reinterpret_cast<const float4*>(lds + ofs);   // ds_read_b128, imm offset
}
template <int EB>
__device__ __forceinline__ void fma4(float4 w, const f2 (&e)[EPAD], f2& s) {
    s.x = fmaf(w.x, e[EB+0].x, s.x); s.y = fmaf(w.x, e[EB+0].y, s.y);
    s.x = fmaf(w.y, e[EB+1].x, s.x); s.y = fmaf(w.y, e[EB+1].y, s.y);
    s.x = fmaf(w.z, e[EB+2].x, s.x); s.y = fmaf(w.z, e[EB+2].y, s.y);
    s.x = fmaf(w.w, e[EB+3].x, s.x); s.y = fmaf(w.w, e[EB+3].y, s.y);
}
template <int I, size_t... Qs>
__device__ __forceinline__ f2 row_sum(const float* lds, const f2 (&e)[EPAD],
                                      std::index_sequence<Qs...>) {
    f2 s{0.f, 0.f};
    ((fma4<I + 1 + 4*(int)Qs>(ld4(lds, rowstart(I) + 4*(int)Qs), e, s)), ...);
    return s;
}
template <size_t... Is>
__device__ __forceinline__ f2 pair_sum(const float* lds, const f2 (&e)[EPAD],
                                       std::index_sequence<Is...>) {
    f2 acc0{0.f, 0.f}, acc1{0.f, 0.f};
    ((void)[&]{
        f2 inner = row_sum<(int)Is>(lds, e,
                       std::make_index_sequence<(size_t)(rowlen((int)Is)/4)>{});
        f2& a = (Is & 1) ? acc1 : acc0;
        a.x = fmaf(e[Is].x, inner.x, a.x);
        a.y = fmaf(e[Is].y, inner.y, a.y);
    }(), ...);
    return f2{acc0.x + acc1.x, acc0.y + acc1.y};
}
template <size_t... Fs>
__device__ __forceinline__ void load_idx(const int* __restrict__ rowIdx,
                                         int (&idx)[FIELD], std::index_sequence<Fs...>) {
    ((idx[Fs] = rowIdx[Fs]), ...);                        // merged dwordx4
}
template <size_t... Fs>
__device__ __forceinline__ void gather_all(const int (&idx)[FIELD],
                                           const float* __restrict__ emb,
                                           int dh2, f2 (&e)[EPAD],
                                           std::index_sequence<Fs...>) {
    // 8 lanes x 8B cover one 64B emb row; 8 rows per wave instruction = 8 lines.
    ((e[Fs] = *reinterpret_cast<const f2*>(emb + (size_t)idx[Fs] * DIM + dh2)), ...);
}

// 8 rows/wave, 2 dims/lane. Weight quads in LDS; each ds_read_b128 now feeds
// two dims -> per-dim LDS instruction cost halved vs the 4-rows/wave layout.
__global__ __launch_bounds__(256, 1) void fwfm_kernel(
    const int*   __restrict__ inputs,   // [BATCH][FIELD]
    const float* __restrict__ emb,      // [1M][DIM]
    const float* __restrict__ fw,       // [741]
    const float* __restrict__ lw,       // [1M]
    const float* __restrict__ bias,     // [1]
    float*       __restrict__ out)      // [BATCH]
{
    __shared__ __align__(16) float wlds[WTOT];            // 3.2 KB

    const int tid  = threadIdx.x;
    const int lane = tid & 63;
    const int wave = tid >> 6;
    const int dh   = lane & 7;                  // dim-pair owned by this lane
    const int rloc = lane >> 3;                 // row within wave (0..7)
    const int row  = blockIdx.x * 32 + wave * RPW + rloc;

    const int* rowIdx = inputs + row * FIELD;

    // ---- issue the long-latency random gathers FIRST ----
    int idx[FIELD];
    load_idx(rowIdx, idx, std::make_index_sequence<FIELD>{});
    f2 e[EPAD];
    gather_all(idx, emb, dh * 2, e, std::make_index_sequence<FIELD>{});
    e[39] = f2{0.f, 0.f}; e[40] = f2{0.f, 0.f}; e[41] = f2{0.f, 0.f};

    // ---- first order: 39 fields split across the 8 dim-lanes (4 or 5 each) ----
    float fo = lw[idx[dh]] + lw[idx[dh + 8]] + lw[idx[dh + 16]] + lw[idx[dh + 24]];
    if (dh < 7) fo += lw[idx[dh + 32]];

    // ---- stage packed weights into LDS (overlaps gather latency) ----
    for (int s = tid; s < WTOT; s += 256) {
        int m = g_map.v[s];
        wlds[s] = (m >= 0) ? fw[m] : 0.f;
    }
    __syncthreads();

    // ---- second order: 38 padded weight rows, float2 dims ----
    f2 so = pair_sum(wlds, e, std::make_index_sequence<FIELD - 1>{});

    // ---- reduce the 8 dim-pair lanes of this row (xor within dh bits) ----
    float tot = so.x + so.y + fo;
    tot += __shfl_xor(tot, 1, 64);
    tot += __shfl_xor(tot, 2, 64);
    tot += __shfl_xor(tot, 4, 64);

    if (dh == 0) out[row] = tot + bias[0];
}

extern "C" void kernel_launch(void* const* d_in, const int* in_sizes, int n_in,
                              void* d_out, int out_size, void* d_ws, size_t ws_size,
                              hipStream_t stream) {
    const int*   inputs = (const int*)  d_in[0];
    const float* emb    = (const float*)d_in[1];
    const float* fw     = (const float*)d_in[2];
    const float* lw     = (const float*)d_in[3];
    const float* bias   = (const float*)d_in[4];
    float*       out    = (float*)      d_out;

    dim3 grid(BATCH / 32);   // 256 blocks * 4 waves * 8 rows = 8192 rows
    fwfm_kernel<<<grid, 256, 0, stream>>>(inputs, emb, fw, lw, bias, out);
}